// Round 2
// baseline (680.463 us; speedup 1.0000x reference)
//
#include <hip/hip_runtime.h>
#include <math.h>

// FlashMoERouter fused kernel (fp32 VALU GEMM + fused router epilogue).
// Shapes: x[16384,4096], W = concat(gate_w[64,4096], cap_w1[64,4096]) -> C[16384,128]
// Epilogue per row: scores = C[:, :64]; h = C[:, 64:] + cap_b1; LN -> GELU(exact) ->
// dot(cap_w2)+cap_b2 -> sigmoid = capacity; gated = (scores - 0.1*lb)*capacity*max(temp,0.1);
// top-2 scatter + renormalize by (v1+v2+1e-6).

#define NTOK   16384
#define DDIM   4096
#define NEXP   64
#define NCOL   128
#define KTILE  64
#define BROWS  64
#define NTHR   512
#define NKT    (DDIM / KTILE)   // 64

__device__ __forceinline__ float wsum64(float v) {
#pragma unroll
  for (int m = 1; m < 64; m <<= 1) v += __shfl_xor(v, m, 64);
  return v;
}

__device__ __forceinline__ void wmax64(float& v, int& i) {
  // max with lowest-index tie-break (matches jax.lax.top_k ordering)
#pragma unroll
  for (int m = 1; m < 64; m <<= 1) {
    float ov = __shfl_xor(v, m, 64);
    int   oi = __shfl_xor(i, m, 64);
    if (ov > v || (ov == v && oi < i)) { v = ov; i = oi; }
  }
}

__global__ void __launch_bounds__(NTHR, 1)
moe_router(const float* __restrict__ x,
           const float* __restrict__ gate_w,
           const float* __restrict__ cap_w1,
           const float* __restrict__ cap_b1,
           const float* __restrict__ ln_g,
           const float* __restrict__ ln_b,
           const float* __restrict__ cap_w2,
           const float* __restrict__ cap_b2,
           const float* __restrict__ temperature,
           const float* __restrict__ usage,
           float* __restrict__ out)
{
  // 128 KB static LDS total (<=160 KB/CU): 1 block/CU, 8 waves.
  __shared__ float Xs[2][BROWS * KTILE];   // [row][k] linear, 2x16KB
  __shared__ float Ws[2][NCOL * KTILE];    // [c][k] w/ 16B-chunk XOR swizzle, 2x32KB
  __shared__ float Cs[BROWS * NCOL];       // epilogue staging, 32KB

  const int t   = threadIdx.x;
  const int tc4 = t & 31;   // col group (4 cols each)
  const int tr4 = t >> 5;   // row group (4 rows each)
  const int r0  = blockIdx.x * BROWS;

  float4 xst[2], wst[4];    // staging registers (global -> reg -> LDS)

  auto stage_load = [&](int kt) {
    const int kb = kt * KTILE;
#pragma unroll
    for (int it = 0; it < 2; ++it) {
      const int p   = it * (NTHR * 4) + t * 4;   // float idx in 64x64 tile
      const int row = p >> 6;
      const int ko  = p & 63;
      xst[it] = *(const float4*)&x[(size_t)(r0 + row) * DDIM + kb + ko];
    }
#pragma unroll
    for (int it = 0; it < 4; ++it) {
      const int c  = (t >> 4) + 32 * it;        // combined col 0..127
      const int k0 = (t & 15) * 4;
      const float* src = (c < NEXP) ? &gate_w[(size_t)c * DDIM]
                                    : &cap_w1[(size_t)(c - NEXP) * DDIM];
      wst[it] = *(const float4*)&src[kb + k0];
    }
  };

  auto stage_write = [&](int b) {
#pragma unroll
    for (int it = 0; it < 2; ++it) {
      const int p = it * (NTHR * 4) + t * 4;
      *(float4*)&Xs[b][p] = xst[it];            // linear: conflict-free b128 writes
    }
#pragma unroll
    for (int it = 0; it < 4; ++it) {
      const int c   = (t >> 4) + 32 * it;
      const int k0  = (t & 15) * 4;
      // XOR-swizzle the 16B chunk index with bits of (c>>2) so compute-phase
      // per-k reads across 32 lanes spread over all bank quads (else 32-way).
      const int idx = (c * KTILE + k0) ^ (((c >> 2) & 7) << 2);
      *(float4*)&Ws[b][idx] = wst[it];
    }
  };

  float acc[4][4];
#pragma unroll
  for (int i = 0; i < 4; ++i)
#pragma unroll
    for (int j = 0; j < 4; ++j) acc[i][j] = 0.0f;

  stage_load(0);
  stage_write(0);
  __syncthreads();

  int buf = 0;
  for (int kt = 0; kt < NKT; ++kt) {
    if (kt + 1 < NKT) stage_load(kt + 1);   // issue next-tile global loads early

    const float* Xb = Xs[buf];
    const float* Wb = Ws[buf];
    const int wswz = (tc4 & 7) << 2;        // read-side swizzle, same key as write

    // two-level accumulation (tile-local then global) to keep fp32 rounding
    // ~1e-6 so top-2 selection matches the numpy reference.
    float ta[4][4];
#pragma unroll
    for (int i = 0; i < 4; ++i)
#pragma unroll
      for (int j = 0; j < 4; ++j) ta[i][j] = 0.0f;

#pragma unroll 4
    for (int kg = 0; kg < KTILE / 4; ++kg) {
      float4 xv[4], wv[4];
#pragma unroll
      for (int i = 0; i < 4; ++i)
        xv[i] = *(const float4*)&Xb[(tr4 * 4 + i) * KTILE + kg * 4];
#pragma unroll
      for (int j = 0; j < 4; ++j)
        wv[j] = *(const float4*)&Wb[(((tc4 * 4 + j) * KTILE) + kg * 4) ^ wswz];
#pragma unroll
      for (int i = 0; i < 4; ++i) {
#pragma unroll
        for (int j = 0; j < 4; ++j) {
          ta[i][j] = fmaf(xv[i].x, wv[j].x, ta[i][j]);
          ta[i][j] = fmaf(xv[i].y, wv[j].y, ta[i][j]);
          ta[i][j] = fmaf(xv[i].z, wv[j].z, ta[i][j]);
          ta[i][j] = fmaf(xv[i].w, wv[j].w, ta[i][j]);
        }
      }
    }

#pragma unroll
    for (int i = 0; i < 4; ++i)
#pragma unroll
      for (int j = 0; j < 4; ++j) acc[i][j] += ta[i][j];

    if (kt + 1 < NKT) stage_write(buf ^ 1); // other buffer: no race with readers
    __syncthreads();
    buf ^= 1;
  }

  // ---- epilogue: park C tile in LDS, then one wave per row ----
#pragma unroll
  for (int i = 0; i < 4; ++i) {
    float4 v = make_float4(acc[i][0], acc[i][1], acc[i][2], acc[i][3]);
    *(float4*)&Cs[(tr4 * 4 + i) * NCOL + tc4 * 4] = v;
  }
  __syncthreads();

  const int wave = t >> 6;
  const int lane = t & 63;
  const float cb1v = cap_b1[lane];
  const float lgv  = ln_g[lane];
  const float lbtv = ln_b[lane];
  const float cw2v = cap_w2[lane];
  const float usv  = usage[lane];
  const float usum = wsum64(usv) + 1e-6f;
  const float lbv  = usv / usum;
  const float tcl  = fmaxf(temperature[0], 0.1f);
  const float cb2v = cap_b2[0];

#pragma unroll
  for (int rr = 0; rr < 8; ++rr) {
    const int row = wave * 8 + rr;
    const float sc = Cs[row * NCOL + lane];
    const float h  = Cs[row * NCOL + 64 + lane] + cb1v;
    const float mean = wsum64(h) * (1.0f / 64.0f);
    const float d    = h - mean;
    const float var  = wsum64(d * d) * (1.0f / 64.0f);
    const float hn   = d * rsqrtf(var + 1e-5f) * lgv + lbtv;
    const float ge   = 0.5f * hn * (1.0f + erff(hn * 0.70710678118654752f));
    float cap = wsum64(ge * cw2v) + cb2v;
    cap = 1.0f / (1.0f + expf(-cap));
    const float gated = (sc - 0.1f * lbv) * cap * tcl;

    float v1 = gated; int i1 = lane;
    wmax64(v1, i1);
    float v2 = (lane == i1) ? -INFINITY : gated;
    int   i2 = lane;
    wmax64(v2, i2);

    const float denom = v1 + v2 + 1e-6f;
    float r = 0.0f;
    if (lane == i1)       r = v1 / denom;
    else if (lane == i2)  r = v2 / denom;
    out[(size_t)(r0 + row) * NEXP + lane] = r;
  }
}

extern "C" void kernel_launch(void* const* d_in, const int* in_sizes, int n_in,
                              void* d_out, int out_size, void* d_ws, size_t ws_size,
                              hipStream_t stream) {
  const float* x           = (const float*)d_in[0];
  const float* gate_w      = (const float*)d_in[1];
  const float* cap_w1      = (const float*)d_in[2];
  const float* cap_b1      = (const float*)d_in[3];
  const float* ln_g        = (const float*)d_in[4];
  const float* ln_b        = (const float*)d_in[5];
  const float* cap_w2      = (const float*)d_in[6];
  const float* cap_b2      = (const float*)d_in[7];
  const float* temperature = (const float*)d_in[8];
  const float* usage       = (const float*)d_in[9];
  float* out = (float*)d_out;

  dim3 grid(NTOK / BROWS);   // 256 blocks = 1 per CU
  dim3 block(NTHR);
  moe_router<<<grid, block, 0, stream>>>(x, gate_w, cap_w1, cap_b1, ln_g, ln_b,
                                         cap_w2, cap_b2, temperature, usage, out);
}

// Round 4
// 470.546 us; speedup vs baseline: 1.4461x; 1.4461x over previous
//
#include <hip/hip_runtime.h>
#include <math.h>

// FlashMoERouter: int8-limb MFMA GEMM + fused router epilogue.
// C[16384,128] = x[16384,4096] . W^T, W = concat(gate_w, cap_w1) [128,4096].
// Exactness: x ~= qx/2^19, w ~= qw/2^24 with qx,qw int (RNE). qx = X0*2^16+X1*2^8+X2
// (signed int8 limbs, exact). Keep limb products with weight >= 2^8:
//   acc0=X0Y0, acc1=X0Y1+X1Y0, acc2=X0Y2+X1Y1+X2Y0, acc3=X1Y2+X2Y1  (int32, exact)
// dropped X2Y2 term -> score error ~4e-8 (below fp32 reference noise).
// score = (acc0<<24 | acc1<<16 | acc2<<8 | acc3) * 2^-35  (int64 exact, then double).

#define NTOK 16384
#define DDIM 4096
#define NEXP 64
#define NCOL 128
#define BM   64
#define KT   64
#define NKT  (DDIM / KT)    // 64
#define NTHR 512
#define ASTR 80             // A-plane row stride in bytes (bank-decorrelating)
#define WPLANE (NCOL * DDIM) // 524288 B per W limb plane in d_ws

typedef int i32x4 __attribute__((ext_vector_type(4)));

__device__ __forceinline__ void split3(float v, float scale, int& X0, int& X1, int& X2) {
  // q = round-to-nearest-even(v*scale), |q| < 2^22 required.
  float b = fmaf(v, scale, 12582912.0f);     // 1.5*2^23 magic bias
  int q = __float_as_int(b) - 0x4B400000;
  X2 = (int)(signed char)(q & 0xff);
  int q1 = (q - X2) >> 8;
  X1 = (int)(signed char)(q1 & 0xff);
  X0 = (q1 - X1) >> 8;                        // |X0| <= ~49 (x), ~29 (w)
}

__device__ __forceinline__ unsigned pack4(int a, int b, int c, int d) {
  return (unsigned)(a & 0xff) | ((unsigned)(b & 0xff) << 8) |
         ((unsigned)(c & 0xff) << 16) | ((unsigned)(d & 0xff) << 24);
}

// ---- prep: quantize W rows (gate_w ++ cap_w1) into 3 int8 limb planes in ws ----
__global__ void __launch_bounds__(256)
prep_w(const float* __restrict__ gw, const float* __restrict__ cw1,
       signed char* __restrict__ wq) {
  const int c = blockIdx.x;                   // 0..127 (output col / W row)
  const float* src = (c < NEXP) ? gw + (size_t)c * DDIM
                                : cw1 + (size_t)(c - NEXP) * DDIM;
  const int t = threadIdx.x;
#pragma unroll
  for (int i = 0; i < 4; ++i) {
    const int j = t * 16 + i * 4;
    float4 v = *(const float4*)&src[j];
    int a0,a1,a2, b0,b1,b2, c0,c1,c2, d0,d1,d2;
    split3(v.x, 16777216.0f, a0, a1, a2);     // 2^24
    split3(v.y, 16777216.0f, b0, b1, b2);
    split3(v.z, 16777216.0f, c0, c1, c2);
    split3(v.w, 16777216.0f, d0, d1, d2);
    *(unsigned*)(wq + 0 * WPLANE + (size_t)c * DDIM + j) = pack4(a0, b0, c0, d0);
    *(unsigned*)(wq + 1 * WPLANE + (size_t)c * DDIM + j) = pack4(a1, b1, c1, d1);
    *(unsigned*)(wq + 2 * WPLANE + (size_t)c * DDIM + j) = pack4(a2, b2, c2, d2);
  }
}

__device__ __forceinline__ float wsum64(float v) {
#pragma unroll
  for (int m = 1; m < 64; m <<= 1) v += __shfl_xor(v, m, 64);
  return v;
}

__device__ __forceinline__ void wmax64(float& v, int& i) {
#pragma unroll
  for (int m = 1; m < 64; m <<= 1) {
    float ov = __shfl_xor(v, m, 64);
    int   oi = __shfl_xor(i, m, 64);
    if (ov > v || (ov == v && oi < i)) { v = ov; i = oi; }
  }
}

#define MM(A_, B_, C_) C_ = __builtin_amdgcn_mfma_i32_16x16x64_i8(A_, B_, C_, 0, 0, 0)

__global__ void __launch_bounds__(NTHR, 2)
moe_router_mfma(const float* __restrict__ x,
                const signed char* __restrict__ wq,
                const float* __restrict__ cap_b1,
                const float* __restrict__ ln_g,
                const float* __restrict__ ln_b,
                const float* __restrict__ cap_w2,
                const float* __restrict__ cap_b2,
                const float* __restrict__ temperature,
                const float* __restrict__ usage,
                float* __restrict__ out)
{
  __shared__ signed char Aq[2][3][BM * ASTR];  // 2 bufs x 3 limb planes, 30.7 KB
  __shared__ float Cs[BM * 132];               // padded C tile, 33.8 KB

  const int t    = threadIdx.x;
  const int r0   = blockIdx.x * BM;
  const int lane = t & 63;
  const int wv   = t >> 6;        // 0..7
  const int wr   = wv >> 2;       // 0..1  (row half: 32 rows)
  const int wc   = wv & 3;        // 0..3  (col quarter: 32 cols)
  const int l15  = lane & 15;
  const int l4   = lane >> 4;     // 0..3

  // x staging: 2 float4/thread covering the 64x64 f32 tile
  const int xrow0 = t >> 4,          xc0 = t & 15;
  const int xrow1 = (t + 512) >> 4,  xc1 = t & 15;

  float4 xv0, xv1;
  auto xload = [&](int kt) {
    const float* xb = x + (size_t)r0 * DDIM + kt * KT;
    xv0 = *(const float4*)&xb[(size_t)xrow0 * DDIM + xc0 * 4];
    xv1 = *(const float4*)&xb[(size_t)xrow1 * DDIM + xc1 * 4];
  };
  auto xquant = [&](int buf) {
    int a0,a1,a2, b0,b1,b2, c0,c1,c2, d0,d1,d2;
    split3(xv0.x, 524288.0f, a0, a1, a2);      // 2^19
    split3(xv0.y, 524288.0f, b0, b1, b2);
    split3(xv0.z, 524288.0f, c0, c1, c2);
    split3(xv0.w, 524288.0f, d0, d1, d2);
    *(unsigned*)&Aq[buf][0][xrow0 * ASTR + xc0 * 4] = pack4(a0, b0, c0, d0);
    *(unsigned*)&Aq[buf][1][xrow0 * ASTR + xc0 * 4] = pack4(a1, b1, c1, d1);
    *(unsigned*)&Aq[buf][2][xrow0 * ASTR + xc0 * 4] = pack4(a2, b2, c2, d2);
    split3(xv1.x, 524288.0f, a0, a1, a2);
    split3(xv1.y, 524288.0f, b0, b1, b2);
    split3(xv1.z, 524288.0f, c0, c1, c2);
    split3(xv1.w, 524288.0f, d0, d1, d2);
    *(unsigned*)&Aq[buf][0][xrow1 * ASTR + xc1 * 4] = pack4(a0, b0, c0, d0);
    *(unsigned*)&Aq[buf][1][xrow1 * ASTR + xc1 * 4] = pack4(a1, b1, c1, d1);
    *(unsigned*)&Aq[buf][2][xrow1 * ASTR + xc1 * 4] = pack4(a2, b2, c2, d2);
  };

  i32x4 Ba[2][3], Bb[2][3];
  auto bload = [&](int kt, i32x4 (&B)[2][3]) {
#pragma unroll
    for (int fc = 0; fc < 2; ++fc) {
      const int col = wc * 32 + fc * 16 + l15;
      const signed char* bp = wq + (size_t)col * DDIM + kt * KT + l4 * 16;
#pragma unroll
      for (int lb = 0; lb < 3; ++lb)
        B[fc][lb] = *(const i32x4*)(bp + (size_t)lb * WPLANE);
    }
  };

  i32x4 acc[2][2][4];                          // [fr][fc][plane]
  const i32x4 zz = {0, 0, 0, 0};
#pragma unroll
  for (int fr = 0; fr < 2; ++fr)
#pragma unroll
    for (int fc = 0; fc < 2; ++fc)
#pragma unroll
      for (int p = 0; p < 4; ++p) acc[fr][fc][p] = zz;

  // prologue
  xload(0);
  xquant(0);
  bload(0, Ba);
  __syncthreads();

  auto step = [&](int kt, i32x4 (&Bu)[2][3], i32x4 (&Bp)[2][3]) {
    const int buf = kt & 1;
    if (kt + 1 < NKT) { xload(kt + 1); bload(kt + 1, Bp); }

    i32x4 Af[2][3];
#pragma unroll
    for (int fr = 0; fr < 2; ++fr) {
      const int row = wr * 32 + fr * 16 + l15;
#pragma unroll
      for (int lb = 0; lb < 3; ++lb)
        Af[fr][lb] = *(const i32x4*)&Aq[buf][lb][row * ASTR + l4 * 16];
    }

    // 8 limb products x 4 frags; grouped by product so same-acc MFMAs are spaced
#pragma unroll
    for (int fr = 0; fr < 2; ++fr)
#pragma unroll
      for (int fc = 0; fc < 2; ++fc) MM(Af[fr][0], Bu[fc][0], acc[fr][fc][0]);
#pragma unroll
    for (int fr = 0; fr < 2; ++fr)
#pragma unroll
      for (int fc = 0; fc < 2; ++fc) MM(Af[fr][0], Bu[fc][1], acc[fr][fc][1]);
#pragma unroll
    for (int fr = 0; fr < 2; ++fr)
#pragma unroll
      for (int fc = 0; fc < 2; ++fc) MM(Af[fr][1], Bu[fc][0], acc[fr][fc][1]);
#pragma unroll
    for (int fr = 0; fr < 2; ++fr)
#pragma unroll
      for (int fc = 0; fc < 2; ++fc) MM(Af[fr][0], Bu[fc][2], acc[fr][fc][2]);
#pragma unroll
    for (int fr = 0; fr < 2; ++fr)
#pragma unroll
      for (int fc = 0; fc < 2; ++fc) MM(Af[fr][1], Bu[fc][1], acc[fr][fc][2]);
#pragma unroll
    for (int fr = 0; fr < 2; ++fr)
#pragma unroll
      for (int fc = 0; fc < 2; ++fc) MM(Af[fr][2], Bu[fc][0], acc[fr][fc][2]);
#pragma unroll
    for (int fr = 0; fr < 2; ++fr)
#pragma unroll
      for (int fc = 0; fc < 2; ++fc) MM(Af[fr][1], Bu[fc][2], acc[fr][fc][3]);
#pragma unroll
    for (int fr = 0; fr < 2; ++fr)
#pragma unroll
      for (int fc = 0; fc < 2; ++fc) MM(Af[fr][2], Bu[fc][1], acc[fr][fc][3]);

    if (kt + 1 < NKT) xquant(buf ^ 1);   // writes other buffer: no race
    __syncthreads();
  };

  for (int kt = 0; kt < NKT; kt += 2) {
    step(kt,     Ba, Bb);
    step(kt + 1, Bb, Ba);
  }

  // ---- recombine limb accumulators (exact int64) and park C in LDS ----
#pragma unroll
  for (int fr = 0; fr < 2; ++fr)
#pragma unroll
    for (int fc = 0; fc < 2; ++fc)
#pragma unroll
      for (int r = 0; r < 4; ++r) {
        long tot = (((long)acc[fr][fc][0][r]) << 24) + (((long)acc[fr][fc][1][r]) << 16)
                 + (((long)acc[fr][fc][2][r]) << 8)  +  ((long)acc[fr][fc][3][r]);
        const float sc = (float)((double)tot * 2.9103830456733704e-11); // 2^-35
        const int row = wr * 32 + fr * 16 + l4 * 4 + r;
        const int col = wc * 32 + fc * 16 + l15;
        Cs[row * 132 + col] = sc;
      }
  __syncthreads();

  // ---- router epilogue: one wave per row (lane = expert) ----
  const float cb1v = cap_b1[lane];
  const float lgv  = ln_g[lane];
  const float lbtv = ln_b[lane];
  const float cw2v = cap_w2[lane];
  const float usv  = usage[lane];
  const float usum = wsum64(usv) + 1e-6f;
  const float lbv  = usv / usum;
  const float tcl  = fmaxf(temperature[0], 0.1f);
  const float cb2v = cap_b2[0];

#pragma unroll
  for (int rr = 0; rr < 8; ++rr) {
    const int row = wv * 8 + rr;
    const float sc = Cs[row * 132 + lane];
    const float h  = Cs[row * 132 + 64 + lane] + cb1v;
    const float mean = wsum64(h) * (1.0f / 64.0f);
    const float d    = h - mean;
    const float var  = wsum64(d * d) * (1.0f / 64.0f);
    const float hn   = d * rsqrtf(var + 1e-5f) * lgv + lbtv;
    const float ge   = 0.5f * hn * (1.0f + erff(hn * 0.70710678118654752f));
    float cap = wsum64(ge * cw2v) + cb2v;
    cap = 1.0f / (1.0f + expf(-cap));
    const float gated = (sc - 0.1f * lbv) * cap * tcl;

    float v1 = gated; int i1 = lane;
    wmax64(v1, i1);
    float v2 = (lane == i1) ? -INFINITY : gated;
    int   i2 = lane;
    wmax64(v2, i2);

    const float denom = v1 + v2 + 1e-6f;
    float r = 0.0f;
    if (lane == i1)      r = v1 / denom;
    else if (lane == i2) r = v2 / denom;
    out[(size_t)(r0 + row) * NEXP + lane] = r;
  }
}

extern "C" void kernel_launch(void* const* d_in, const int* in_sizes, int n_in,
                              void* d_out, int out_size, void* d_ws, size_t ws_size,
                              hipStream_t stream) {
  const float* x           = (const float*)d_in[0];
  const float* gate_w      = (const float*)d_in[1];
  const float* cap_w1      = (const float*)d_in[2];
  const float* cap_b1      = (const float*)d_in[3];
  const float* ln_g        = (const float*)d_in[4];
  const float* ln_b        = (const float*)d_in[5];
  const float* cap_w2      = (const float*)d_in[6];
  const float* cap_b2      = (const float*)d_in[7];
  const float* temperature = (const float*)d_in[8];
  const float* usage       = (const float*)d_in[9];
  float* out = (float*)d_out;
  signed char* wq = (signed char*)d_ws;        // needs 3*WPLANE = 1.5 MB

  prep_w<<<dim3(NCOL), dim3(256), 0, stream>>>(gate_w, cap_w1, wq);
  moe_router_mfma<<<dim3(NTOK / BM), dim3(NTHR), 0, stream>>>(
      x, wq, cap_b1, ln_g, ln_b, cap_w2, cap_b2, temperature, usage, out);
}